// Round 7
// baseline (415.022 us; speedup 1.0000x reference)
//
#include <hip/hip_runtime.h>

#define N_TOK 16384
#define KCB   16384
#define DIM   256
#define HW    1024
#define DECAYF 0.8f
#define ONE_M_DECAY 0.2f
#define BETAF 0.25f
#define EPSF  1e-5f
#define STRIPS 8
#define KB_PER 16

typedef __attribute__((ext_vector_type(8))) short bf16x8;
typedef __attribute__((ext_vector_type(4))) float f32x4;

__device__ __forceinline__ float wave_reduce_sum(float s) {
    #pragma unroll
    for (int o = 32; o > 0; o >>= 1) s += __shfl_down(s, o);
    return s;
}

__device__ __forceinline__ unsigned short f2bf(float x) {
    union { float f; unsigned int u; } a; a.f = x;
    unsigned int r = a.u + 0x7fffu + ((a.u >> 16) & 1u);
    return (unsigned short)(r >> 16);
}

// ---- K1: transpose z[b][c][hw] -> zf[n][d] (fp32) + Ah[n][d] (bf16) ----
__global__ void k_transpose_z(const float* __restrict__ z, float* __restrict__ zf,
                              unsigned short* __restrict__ Ah) {
    __shared__ float t[32][33];
    int b  = blockIdx.z;
    int c0 = blockIdx.y * 32;
    int h0 = blockIdx.x * 32;
    int tid = threadIdx.x;
    int jx = tid & 31, iy = tid >> 5;
    const float* zb = z + (size_t)b * DIM * HW;
    #pragma unroll
    for (int p = 0; p < 4; ++p) {
        int ci = iy + p * 8;
        t[ci][jx] = zb[(size_t)(c0 + ci) * HW + h0 + jx];
    }
    __syncthreads();
    #pragma unroll
    for (int p = 0; p < 4; ++p) {
        int hh = iy + p * 8;
        size_t idx = (size_t)(b * HW + h0 + hh) * DIM + c0 + jx;
        float v = t[jx][hh];
        zf[idx] = v;
        Ah[idx] = f2bf(v);
    }
}

// ---- K2: blocks <4096: Bh = bf16(w), wnorm = |w_k|^2; blocks >=4096: sum(cs) ----
__global__ void k_prep_w(const float* __restrict__ w, unsigned short* __restrict__ Bh,
                         float* __restrict__ wnorm, const float* __restrict__ cs,
                         float* __restrict__ scal) {
    int lane = threadIdx.x & 63;
    if (blockIdx.x < 4096) {
        int wv = blockIdx.x * 4 + (threadIdx.x >> 6);
        float4 v = ((const float4*)(w + (size_t)wv * DIM))[lane];
        ushort4 h;
        h.x = f2bf(v.x); h.y = f2bf(v.y); h.z = f2bf(v.z); h.w = f2bf(v.w);
        ((ushort4*)(Bh + (size_t)wv * DIM))[lane] = h;
        float s = v.x * v.x + v.y * v.y + v.z * v.z + v.w * v.w;
        s = wave_reduce_sum(s);
        if (lane == 0) wnorm[wv] = s;
    } else {
        int i = (blockIdx.x - 4096) * 256 + threadIdx.x;
        float v = cs[i];
        v = wave_reduce_sum(v);
        if (lane == 0) atomicAdd(&scal[1], v);
    }
}

// ---- K3: bf16 MFMA GEMM; A-frags register-resident, B double-buffered in LDS ----
// grid (128 n-tiles, 8 strips). packed score as before:
// u = bits(score+0.0625) & ~0x7FF | (kbi<<7 | half<<6 | nt<<4 | r16)
__global__ __launch_bounds__(256, 2) void k_gemm_argmin(
    const unsigned short* __restrict__ Ah, const unsigned short* __restrict__ Bh,
    const float* __restrict__ wnorm, uint2* __restrict__ pout) {
    __shared__ unsigned short Bs[2][128 * 64];   // 2 x 16 KB double buffer
    __shared__ unsigned int red1[256];
    __shared__ unsigned int red2[256];

    int tid  = threadIdx.x;
    int wave = tid >> 6, lane = tid & 63;
    int g16  = lane >> 4, r16 = lane & 15;
    int n0   = blockIdx.x * 128;
    int strip = blockIdx.y;

    // ---- all 32 A-frags straight from global into VGPRs (L2-served, 64B-coalesced)
    bf16x8 af[8][4];
    #pragma unroll
    for (int ks = 0; ks < 8; ++ks)
        #pragma unroll
        for (int mt = 0; mt < 4; ++mt) {
            int row = n0 + (wave >> 1) * 64 + mt * 16 + r16;
            af[ks][mt] = *(const bf16x8*)(Ah + (size_t)row * 256 + ks * 32 + g16 * 8);
        }

    unsigned int b1[16], b2[16];
    #pragma unroll
    for (int i = 0; i < 16; ++i) { b1[i] = 0xFFFFFFFFu; b2[i] = 0xFFFFFFFFu; }

    f32x4 acc[4][4];
    #pragma unroll
    for (int mt = 0; mt < 4; ++mt)
        #pragma unroll
        for (int nt = 0; nt < 4; ++nt)
            acc[mt][nt] = (f32x4){0.f, 0.f, 0.f, 0.f};

    // prologue: stage (kbi=0, kc=0) into buffer 0
    {
        int c0 = strip * KB_PER * 128;
        #pragma unroll
        for (int i = 0; i < 4; ++i) {
            int s = i * 256 + tid;
            int row = s >> 3, sp = (s & 7) ^ (row & 7);
            const unsigned int* gb = (const unsigned int*)(Bh + (size_t)(c0 + row) * 256 + sp * 8);
            unsigned int* lb = (unsigned int*)&Bs[0][s * 8];
            __builtin_amdgcn_global_load_lds((const __attribute__((address_space(1))) unsigned int*)gb,
                                             (__attribute__((address_space(3))) unsigned int*)lb, 16, 0, 0);
        }
    }
    __syncthreads();

    for (int kbi = 0; kbi < KB_PER; ++kbi) {
        int c0 = (strip * KB_PER + kbi) * 128;
        #pragma unroll
        for (int kc = 0; kc < 4; ++kc) {
            // stage next 64-k chunk into the other buffer (hidden behind this chunk's MFMA)
            if (kc < 3 || kbi < KB_PER - 1) {
                int c0n = (kc == 3) ? c0 + 128 : c0;
                int kcn = (kc + 1) & 3;
                #pragma unroll
                for (int i = 0; i < 4; ++i) {
                    int s = i * 256 + tid;
                    int row = s >> 3, sp = (s & 7) ^ (row & 7);
                    const unsigned int* gb =
                        (const unsigned int*)(Bh + (size_t)(c0n + row) * 256 + kcn * 64 + sp * 8);
                    unsigned int* lb = (unsigned int*)&Bs[(kc + 1) & 1][s * 8];
                    __builtin_amdgcn_global_load_lds((const __attribute__((address_space(1))) unsigned int*)gb,
                                                     (__attribute__((address_space(3))) unsigned int*)lb, 16, 0, 0);
                }
            }
            // compute current chunk (B from LDS, A from registers)
            #pragma unroll
            for (int h = 0; h < 2; ++h) {
                bf16x8 bfr[4];
                #pragma unroll
                for (int nt = 0; nt < 4; ++nt) {
                    int row = (wave & 1) * 64 + nt * 16 + r16;
                    int sp = (h * 4 + g16) ^ (row & 7);
                    bfr[nt] = *(const bf16x8*)&Bs[kc & 1][(row * 8 + sp) * 8];
                }
                #pragma unroll
                for (int mt = 0; mt < 4; ++mt)
                    #pragma unroll
                    for (int nt = 0; nt < 4; ++nt)
                        acc[mt][nt] = __builtin_amdgcn_mfma_f32_16x16x32_bf16(
                            af[kc * 2 + h][mt], bfr[nt], acc[mt][nt], 0, 0, 0);
            }
            if (kc == 3) {
                // epilogue for this kbi: 5-op/score packed top-2, then reset acc
                float wnb[4];
                unsigned int orv[4];
                #pragma unroll
                for (int nt = 0; nt < 4; ++nt) {
                    int code = c0 + (wave & 1) * 64 + nt * 16 + r16;
                    wnb[nt] = wnorm[code] + 0.0625f;
                    orv[nt] = (unsigned int)((kbi << 7) | ((wave & 1) << 6) | (nt << 4));
                }
                #pragma unroll
                for (int mt = 0; mt < 4; ++mt)
                    #pragma unroll
                    for (int rg = 0; rg < 4; ++rg) {
                        int i = mt * 4 + rg;
                        #pragma unroll
                        for (int nt = 0; nt < 4; ++nt) {
                            float s = fmaf(-2.0f, acc[mt][nt][rg], wnb[nt]);
                            unsigned int u = (__float_as_uint(s) & 0xFFFFF800u) | orv[nt];
                            unsigned int t = b1[i] > u ? b1[i] : u;
                            b1[i] = b1[i] < u ? b1[i] : u;
                            b2[i] = b2[i] < t ? b2[i] : t;
                        }
                    }
                #pragma unroll
                for (int mt = 0; mt < 4; ++mt)
                    #pragma unroll
                    for (int nt = 0; nt < 4; ++nt)
                        acc[mt][nt] = (f32x4){0.f, 0.f, 0.f, 0.f};
            }
            __syncthreads();
        }
    }

    // attach r16, 16-lane shuffle top-2 merge
    #pragma unroll
    for (int i = 0; i < 16; ++i) {
        unsigned int v1 = b1[i] | (unsigned int)r16;
        unsigned int v2 = b2[i] | (unsigned int)r16;
        #pragma unroll
        for (int off = 1; off < 16; off <<= 1) {
            unsigned int o1 = __shfl_xor((int)v1, off);
            unsigned int o2 = __shfl_xor((int)v2, off);
            unsigned int n1 = v1 < o1 ? v1 : o1;
            unsigned int hi = v1 < o1 ? o1 : v1;
            unsigned int lo = v2 < o2 ? v2 : o2;
            v1 = n1;
            v2 = hi < lo ? hi : lo;
        }
        b1[i] = v1; b2[i] = v2;
    }

    if (r16 == 0) {
        #pragma unroll
        for (int mt = 0; mt < 4; ++mt)
            #pragma unroll
            for (int rg = 0; rg < 4; ++rg) {
                int row = (wave >> 1) * 64 + mt * 16 + g16 * 4 + rg;
                red1[(wave & 1) * 128 + row] = b1[mt * 4 + rg];
                red2[(wave & 1) * 128 + row] = b2[mt * 4 + rg];
            }
    }
    __syncthreads();
    if (tid < 128) {
        unsigned int a1 = red1[tid], a2 = red2[tid];
        unsigned int c1 = red1[128 + tid], c2 = red2[128 + tid];
        unsigned int m1 = a1 < c1 ? a1 : c1;
        unsigned int hi = a1 < c1 ? c1 : a1;
        unsigned int lo = a2 < c2 ? a2 : c2;
        pout[(size_t)strip * N_TOK + n0 + tid] = make_uint2(m1, hi < lo ? hi : lo);
    }
}

// ---- K4: merge strips + exact rescore -> (token, rank), dmin[n]; counts++ ----
__global__ void k_select(const uint2* __restrict__ pout, const float* __restrict__ zf,
                         const float* __restrict__ w, int2* __restrict__ tokrank,
                         float* __restrict__ counts, float* __restrict__ dmin) {
    int n = blockIdx.x * 4 + (threadIdx.x >> 6);
    int lane = threadIdx.x & 63;
    unsigned int c1 = 0xFFFFFFFFu, c2 = 0xFFFFFFFFu;
    int s1 = 0, s2 = 0;
    #pragma unroll
    for (int s = 0; s < STRIPS; ++s) {
        uint2 p = pout[(size_t)s * N_TOK + n];
        if (p.x < c1)      { c2 = c1; s2 = s1; c1 = p.x; s1 = s; }
        else if (p.x < c2) { c2 = p.x; s2 = s; }
        if (p.y < c1)      { c2 = c1; s2 = s1; c1 = p.y; s1 = s; }
        else if (p.y < c2) { c2 = p.y; s2 = s; }
    }
    int code1 = (s1 << 11) | (int)(c1 & 0x7FFu);
    int code2 = (s2 << 11) | (int)(c2 & 0x7FFu);

    float4 zv = ((const float4*)(zf + (size_t)n * DIM))[lane];
    float4 w1 = ((const float4*)(w + (size_t)code1 * DIM))[lane];
    float4 w2 = ((const float4*)(w + (size_t)code2 * DIM))[lane];
    float ax = zv.x - w1.x, ay = zv.y - w1.y, az = zv.z - w1.z, aw = zv.w - w1.w;
    float bx = zv.x - w2.x, by = zv.y - w2.y, bz = zv.z - w2.z, bw = zv.w - w2.w;
    float d1 = ax * ax + ay * ay + az * az + aw * aw;
    float d2 = bx * bx + by * by + bz * bz + bw * bw;
    d1 = wave_reduce_sum(d1);
    d2 = wave_reduce_sum(d2);
    if (lane == 0) {
        bool take2 = (d2 < d1) || (d2 == d1 && code2 < code1);
        int tok = take2 ? code2 : code1;
        dmin[n] = take2 ? d2 : d1;
        float old = atomicAdd(&counts[tok], 1.0f);
        tokrank[n] = make_int2(tok, (int)old);
    }
}

// ---- K5: single-block exclusive prefix sum of counts -> offsets ----
__global__ void k_scan(const float* __restrict__ counts, int* __restrict__ offsets) {
    int tid = threadIdx.x;
    int lane = tid & 63, wv = tid >> 6;
    int base = tid * 64;
    int sum = 0;
    for (int i = 0; i < 64; ++i) sum += (int)counts[base + i];
    int x = sum;
    #pragma unroll
    for (int o = 1; o < 64; o <<= 1) {
        int y = __shfl_up(x, o);
        if (lane >= o) x += y;
    }
    __shared__ int wt[4];
    if (lane == 63) wt[wv] = x;
    __syncthreads();
    int wbase = 0;
    for (int i = 0; i < wv; ++i) wbase += wt[i];
    int run = wbase + x - sum;
    for (int i = 0; i < 64; ++i) {
        offsets[base + i] = run;
        run += (int)counts[base + i];
    }
}

// ---- K6: perm[offsets[tok] + rank] = n ----
__global__ void k_scatter(const int2* __restrict__ tokrank, const int* __restrict__ offsets,
                          int* __restrict__ perm) {
    int n = blockIdx.x * 256 + threadIdx.x;
    int2 tr = tokrank[n];
    perm[offsets[tr.x] + tr.y] = n;
}

// ---- K7: one wave per code: gather z rows, emit embed_avg_new/cluster_new/weight_new ----
__global__ void k_embed(const int* __restrict__ offsets, const float* __restrict__ counts,
                        const int* __restrict__ perm, const float* __restrict__ zf,
                        const float* __restrict__ ea, const float* __restrict__ cs,
                        const float* __restrict__ scal, float* __restrict__ o_embed,
                        float* __restrict__ o_cluster, float* __restrict__ o_wnew) {
    int k = blockIdx.x * 4 + (threadIdx.x >> 6);
    int lane = threadIdx.x & 63;
    int off = offsets[k];
    int c = (int)counts[k];
    float4 acc = make_float4(0.f, 0.f, 0.f, 0.f);
    for (int i = 0; i < c; ++i) {
        int n = perm[off + i];
        float4 zv = ((const float4*)(zf + (size_t)n * DIM))[lane];
        acc.x += zv.x; acc.y += zv.y; acc.z += zv.z; acc.w += zv.w;
    }
    float4 eav = ((const float4*)(ea + (size_t)k * DIM))[lane];
    float4 em = make_float4(DECAYF * eav.x + ONE_M_DECAY * acc.x,
                            DECAYF * eav.y + ONE_M_DECAY * acc.y,
                            DECAYF * eav.z + ONE_M_DECAY * acc.z,
                            DECAYF * eav.w + ONE_M_DECAY * acc.w);
    ((float4*)(o_embed + (size_t)k * DIM))[lane] = em;
    float cn = DECAYF * cs[k] + ONE_M_DECAY * (float)c;
    float ntot = DECAYF * scal[1] + ONE_M_DECAY * (float)N_TOK;
    float sm = (cn + EPSF) / (ntot + (float)KCB * EPSF) * ntot;
    float inv = 1.0f / sm;
    ((float4*)(o_wnew + (size_t)k * DIM))[lane] =
        make_float4(em.x * inv, em.y * inv, em.z * inv, em.w * inv);
    if (lane == 0) o_cluster[k] = cn;
}

// ---- K8: out[b][c][hw] = weight[token[b*HW+hw]][c] ----
__global__ void k_write_out(const int2* __restrict__ tokrank, const float* __restrict__ w,
                            float* __restrict__ out) {
    __shared__ float t[32][33];
    __shared__ int tok[32];
    int b = blockIdx.z, c0 = blockIdx.y * 32, h0 = blockIdx.x * 32;
    int tid = threadIdx.x, jx = tid & 31, iy = tid >> 5;
    if (tid < 32) tok[tid] = tokrank[b * HW + h0 + tid].x;
    __syncthreads();
    #pragma unroll
    for (int p = 0; p < 4; ++p) {
        int hh = iy + p * 8;
        t[hh][jx] = w[(size_t)tok[hh] * DIM + c0 + jx];
    }
    __syncthreads();
    #pragma unroll
    for (int p = 0; p < 4; ++p) {
        int cc = iy + p * 8;
        out[(size_t)b * DIM * HW + (size_t)(c0 + cc) * HW + h0 + jx] = t[jx][cc];
    }
}

// ---- K9: used / plogp / sumsq reductions ----
__global__ void k_stats(const float* __restrict__ counts, const float* __restrict__ dmin,
                        float* __restrict__ scal) {
    int k = blockIdx.x * 256 + threadIdx.x;
    int lane = threadIdx.x & 63;
    float cnt = counts[k];
    float used = cnt > 0.f ? 1.f : 0.f;
    float p = cnt * (1.0f / 16384.0f);
    float pl = p * logf(p + 1e-10f);
    float dv = dmin[k];
    used = wave_reduce_sum(used);
    pl   = wave_reduce_sum(pl);
    dv   = wave_reduce_sum(dv);
    if (lane == 0) {
        atomicAdd(&scal[2], used);
        atomicAdd(&scal[3], pl);
        atomicAdd(&scal[0], dv);
    }
}

// ---- K10: scalar outputs ----
__global__ void k_scalars(const float* __restrict__ scal, float* __restrict__ o_scal) {
    if (threadIdx.x == 0) {
        float sumsq = scal[0], used = scal[2], plogp = scal[3];
        o_scal[0] = BETAF * sumsq / (float)(N_TOK * DIM);
        o_scal[1] = sumsq / (float)N_TOK;
        o_scal[2] = used * (1.0f / (float)KCB);
        o_scal[3] = expf(-plogp);
    }
}

extern "C" void kernel_launch(void* const* d_in, const int* in_sizes, int n_in,
                              void* d_out, int out_size, void* d_ws, size_t ws_size,
                              hipStream_t stream) {
    const float* z  = (const float*)d_in[0];
    const float* w  = (const float*)d_in[1];
    const float* cs = (const float*)d_in[2];
    const float* ea = (const float*)d_in[3];
    float* out = (float*)d_out;

    char* w8 = (char*)d_ws;
    unsigned short* Ah = (unsigned short*)(w8 + 0);          //  8 MB
    unsigned short* Bh = (unsigned short*)(w8 + 8388608);    //  8 MB
    float* wnorm   = (float*)(w8 + 16777216);                // 64 KB
    int2*  tokrank = (int2*)(w8 + 16842752);                 // 128 KB
    float* counts  = (float*)(w8 + 16973824);                // 64 KB (zeroed)
    int*   offsets = (int*)(w8 + 17039360);                  // 64 KB
    int*   perm    = (int*)(w8 + 17104896);                  // 64 KB
    float* scal    = (float*)(w8 + 17170432);                // 64 B (zeroed)
    float* dmin    = (float*)(w8 + 17170496);                // 64 KB

    // aliased into d_out, finalized later in the launch:
    float* zf = out;                                   // [0,16MB): overwritten by k_write_out
    uint2* pout = (uint2*)(out + 4194308);             // 1 MB inside o_wnew; consumed by k_select
    float* o_scal    = out + 4194304;
    float* o_wnew    = out + 4194308;
    float* o_cluster = out + 8388612;
    float* o_embed   = out + 8404996;

    hipMemsetAsync(counts, 0, 17170432 + 64 - 16973824, stream);  // counts..scal
    k_transpose_z<<<dim3(32, 8, 16), 256, 0, stream>>>(z, zf, Ah);
    k_prep_w<<<4160, 256, 0, stream>>>(w, Bh, wnorm, cs, scal);
    k_gemm_argmin<<<dim3(128, STRIPS), 256, 0, stream>>>(Ah, Bh, wnorm, pout);
    k_select<<<4096, 256, 0, stream>>>(pout, zf, w, tokrank, counts, dmin);
    k_scan<<<1, 256, 0, stream>>>(counts, offsets);
    k_scatter<<<64, 256, 0, stream>>>(tokrank, offsets, perm);
    k_embed<<<4096, 256, 0, stream>>>(offsets, counts, perm, zf, ea, cs, scal,
                                      o_embed, o_cluster, o_wnew);
    k_write_out<<<dim3(32, 8, 16), 256, 0, stream>>>(tokrank, w, out);
    k_stats<<<64, 256, 0, stream>>>(counts, dmin, scal);
    k_scalars<<<1, 64, 0, stream>>>(scal, o_scal);
}